// Round 1
// baseline (430.432 us; speedup 1.0000x reference)
//
#include <hip/hip_runtime.h>

// Cross-stitch: out_a = w[c][0][0]*x_a + w[c][0][1]*x_b
//               out_b = w[c][1][0]*x_a + w[c][1][1]*x_b
// Shapes: x_a, x_b : [N=32, C=256, H=64, W=64] fp32, w : [C,2,2] fp32.
// d_out = out_a (N*C*H*W floats) followed by out_b (N*C*H*W floats).
//
// Memory-bound: 536.9 MB total traffic -> ~85 us floor at 6.3 TB/s.
// float4 vectorization; c = (vec4_idx >> 10) & 255 is wave-uniform
// (1024 vec4 per channel-plane, multiple of wave=64).

#define HW4   1024          // (64*64)/4 float4 per (n,c) plane
#define CMASK 255           // C-1, C=256

__global__ __launch_bounds__(256) void cross_stitch_kernel(
    const float4* __restrict__ xa,
    const float4* __restrict__ xb,
    const float*  __restrict__ w,   // [C,2,2] flat
    float4* __restrict__ oa,
    float4* __restrict__ ob,
    int n_vec4)
{
    int i = blockIdx.x * blockDim.x + threadIdx.x;
    if (i >= n_vec4) return;

    int c = (i >> 10) & CMASK;      // wave-uniform channel index
    float w00 = w[c * 4 + 0];
    float w01 = w[c * 4 + 1];
    float w10 = w[c * 4 + 2];
    float w11 = w[c * 4 + 3];

    float4 a = xa[i];
    float4 b = xb[i];

    float4 ra, rb;
    ra.x = w00 * a.x + w01 * b.x;
    ra.y = w00 * a.y + w01 * b.y;
    ra.z = w00 * a.z + w01 * b.z;
    ra.w = w00 * a.w + w01 * b.w;
    rb.x = w10 * a.x + w11 * b.x;
    rb.y = w10 * a.y + w11 * b.y;
    rb.z = w10 * a.z + w11 * b.z;
    rb.w = w10 * a.w + w11 * b.w;

    oa[i] = ra;
    ob[i] = rb;
}

extern "C" void kernel_launch(void* const* d_in, const int* in_sizes, int n_in,
                              void* d_out, int out_size, void* d_ws, size_t ws_size,
                              hipStream_t stream) {
    const float4* xa = (const float4*)d_in[0];
    const float4* xb = (const float4*)d_in[1];
    const float*  w  = (const float*)d_in[2];

    const int n_elem = in_sizes[0];          // 32*256*64*64 = 33,554,432
    const int n_vec4 = n_elem / 4;           // 8,388,608

    float4* oa = (float4*)d_out;
    float4* ob = (float4*)d_out + n_vec4;

    const int block = 256;
    const int grid  = (n_vec4 + block - 1) / block;  // 32768 blocks
    cross_stitch_kernel<<<grid, block, 0, stream>>>(xa, xb, w, oa, ob, n_vec4);
}